// Round 1
// baseline (923.046 us; speedup 1.0000x reference)
//
#include <hip/hip_runtime.h>

#define WAVE 64

// rT layout: [layer][N_R][64]  (batch innermost, matches lane)
__global__ void compute_r_kernel(const float* __restrict__ q,
                                 const float* __restrict__ W1, const float* __restrict__ b1,
                                 const float* __restrict__ W2, const float* __restrict__ b2,
                                 const float* __restrict__ W3, const float* __restrict__ b3,
                                 float* __restrict__ rT, int N_R, int N_W2V) {
    int tid = blockIdx.x * blockDim.x + threadIdx.x;
    int total = 3 * N_R * WAVE;
    if (tid >= total) return;
    int b = tid & 63;
    int j = (tid >> 6) % N_R;
    int l = tid / (N_R * WAVE);
    const float* W  = (l == 0) ? W1 : (l == 1) ? W2 : W3;
    const float* bv = (l == 0) ? b1 : (l == 1) ? b2 : b3;
    float acc = bv[j];
    const float* qrow = q + (size_t)b * N_W2V;
    for (int k = 0; k < N_W2V; ++k)
        acc = fmaf(qrow[k], W[(size_t)k * N_R + j], acc);
    rT[tid] = acc;
}

// x (B=64, N_E) -> xT (N_E, 64), 64x64 LDS tile transpose
__global__ void transpose_in_kernel(const float* __restrict__ in, float* __restrict__ out, int N_E) {
    __shared__ float tile[64][65];
    int e0 = blockIdx.x * 64;
    int li = threadIdx.x & 63;   // inner lane
    int lo = threadIdx.x >> 6;   // 0..3
    #pragma unroll
    for (int k = 0; k < 16; ++k) {
        int b = lo + 4 * k;
        int e = e0 + li;
        tile[b][li] = (e < N_E) ? in[(size_t)b * N_E + e] : 0.0f;
    }
    __syncthreads();
    #pragma unroll
    for (int k = 0; k < 16; ++k) {
        int i = lo + 4 * k;
        int e = e0 + i;
        if (e < N_E) out[(size_t)e * 64 + li] = tile[li][i];
    }
}

// xT (N_E, 64) -> out (B=64, N_E)
__global__ void transpose_out_kernel(const float* __restrict__ in, float* __restrict__ out, int N_E) {
    __shared__ float tile[64][65];
    int e0 = blockIdx.x * 64;
    int li = threadIdx.x & 63;
    int lo = threadIdx.x >> 6;
    #pragma unroll
    for (int k = 0; k < 16; ++k) {
        int i = lo + 4 * k;
        int e = e0 + i;
        tile[i][li] = (e < N_E) ? in[(size_t)e * 64 + li] : 0.0f;  // lane li = batch, coalesced
    }
    __syncthreads();
    #pragma unroll
    for (int k = 0; k < 16; ++k) {
        int b = lo + 4 * k;
        int e = e0 + li;
        if (e < N_E) out[(size_t)b * N_E + e] = tile[li][b];       // lane li = entity, coalesced
    }
}

// One wave per triple; lane = batch row. All buffers in (entity, batch) layout.
__global__ void hop_kernel(const float* __restrict__ xT, const float* __restrict__ rT,
                           const int* __restrict__ subj, const int* __restrict__ rel,
                           const int* __restrict__ obj, float* __restrict__ yT, int nT) {
    int lane   = threadIdx.x & 63;
    int wave   = (blockIdx.x * blockDim.x + threadIdx.x) >> 6;
    int nwaves = (gridDim.x * blockDim.x) >> 6;
    for (int t = wave; t < nT; t += nwaves) {
        int s = subj[t];
        int r = rel[t];
        int o = obj[t];
        float m = xT[(size_t)s * 64 + lane] * rT[(size_t)r * 64 + lane];
        atomicAdd(&yT[(size_t)o * 64 + lane], m);
    }
}

extern "C" void kernel_launch(void* const* d_in, const int* in_sizes, int n_in,
                              void* d_out, int out_size, void* d_ws, size_t ws_size,
                              hipStream_t stream) {
    const float* x  = (const float*)d_in[0];
    const float* q  = (const float*)d_in[1];
    const float* W1 = (const float*)d_in[2];
    const float* b1 = (const float*)d_in[3];
    const float* W2 = (const float*)d_in[4];
    const float* b2 = (const float*)d_in[5];
    const float* W3 = (const float*)d_in[6];
    const float* b3 = (const float*)d_in[7];
    const int* subj = (const int*)d_in[8];
    const int* rel  = (const int*)d_in[9];
    const int* obj  = (const int*)d_in[10];
    // n_hop (d_in[11]) is the constant 3 per the reference; hops hardcoded.

    const int B     = 64;                // == wave size; lane = batch row
    const int N_E   = in_sizes[0] / B;   // 200000
    const int N_W2V = in_sizes[1] / B;   // 300
    const int N_R   = in_sizes[3];       // 200
    const int N_T   = in_sizes[8];       // 1000000

    const size_t xelems = (size_t)N_E * B;
    const size_t xbytes = xelems * sizeof(float);
    const size_t rbytes = (size_t)3 * N_R * B * sizeof(float);

    float* bufA = (float*)d_ws;
    float* bufB;
    float* rT;
    bool b_is_out;
    if (ws_size >= 2 * xbytes + rbytes) {
        bufB = bufA + xelems;
        rT   = bufB + xelems;
        b_is_out = false;
    } else {
        bufB = (float*)d_out;            // use d_out as ping-pong buffer
        rT   = bufA + xelems;
        b_is_out = true;
    }

    // 1) r = q@W + b for all three layers, transposed layout
    {
        int total = 3 * N_R * B;
        compute_r_kernel<<<(total + 255) / 256, 256, 0, stream>>>(
            q, W1, b1, W2, b2, W3, b3, rT, N_R, N_W2V);
    }

    // 2) transpose x -> bufA (entity-major)
    int tgrid = (N_E + 63) / 64;
    transpose_in_kernel<<<tgrid, 256, 0, stream>>>(x, bufA, N_E);

    // 3) three hops, ping-pong
    const int HOP_BLOCKS = 2048;   // 8192 waves, grid-stride over 1M triples
    hipMemsetAsync(bufB, 0, xbytes, stream);
    hop_kernel<<<HOP_BLOCKS, 256, 0, stream>>>(bufA, rT,              subj, rel, obj, bufB, N_T);
    hipMemsetAsync(bufA, 0, xbytes, stream);
    hop_kernel<<<HOP_BLOCKS, 256, 0, stream>>>(bufB, rT + (size_t)1 * N_R * B, subj, rel, obj, bufA, N_T);
    hipMemsetAsync(bufB, 0, xbytes, stream);
    hop_kernel<<<HOP_BLOCKS, 256, 0, stream>>>(bufA, rT + (size_t)2 * N_R * B, subj, rel, obj, bufB, N_T);

    // 4) transpose back to (B, N_E)
    if (!b_is_out) {
        transpose_out_kernel<<<tgrid, 256, 0, stream>>>(bufB, (float*)d_out, N_E);
    } else {
        transpose_out_kernel<<<tgrid, 256, 0, stream>>>(bufB, bufA, N_E);
        hipMemcpyAsync(d_out, bufA, xbytes, hipMemcpyDeviceToDevice, stream);
    }
}